// Round 9
// baseline (885.157 us; speedup 1.0000x reference)
//
#include <hip/hip_runtime.h>

// out[b,n,f] = sum_{l,m} x1[b,l,f] * x2[b,m,f] * cg[l,m,n]
// B=50000, d1=d2=9, d3=25, MUL=512, fp32 in/out.
//
// MFMA formulation: per b, out[n,f] = sum_k W[k,n]*S[k,f], k=(l,m) pad 96;
// S=x1*x2 bf16 in LDS (row/thread, pitch 208B); W=cg bf16 regs;
// mfma_f32_16x16x32_bf16 fp32-accum. No barriers (intra-wave LDS only).
// R7: 858us (NT stores). R8: regular stores 874us -> NT restored.
// Occupancy is LDS-capped at 12 waves/CU; kernel is request-concurrency
// bound (4.0 of 6.3 TB/s). R9: two-deep x prefetch (36 loads in flight,
// ~2 iter bodies of slack) + RPB 10->20 (half the cold prologues).

#define BATCH 50000
#define MUL   512
#define D3    25
#define FCHUNK 256
#define ROWB  208
#define RPB   20

typedef __bf16 bf16x8 __attribute__((ext_vector_type(8)));
typedef float  f32x4  __attribute__((ext_vector_type(4)));

__global__ void __launch_bounds__(256) tp_kernel(
    const float* __restrict__ x1,
    const float* __restrict__ x2,
    const float* __restrict__ cg,
    float* __restrict__ out) {

    extern __shared__ char smem[];

    const int bg    = blockIdx.x >> 1;   // row-group index
    const int chunk = blockIdx.x & 1;    // which 256 f-channels
    const int tid   = threadIdx.x;
    const int lane  = tid & 63;
    const int wv    = tid >> 6;
    const int b0    = bg * RPB;

    const int fl = chunk * FCHUNK + tid;               // this thread's channel
    const float* x1p = x1 + (size_t)b0 * (9 * MUL) + fl;
    const float* x2p = x2 + (size_t)b0 * (9 * MUL) + fl;

    // ---- prologue: issue rows b0, b0+1 loads first (hide under afrag) ----
    float a0[9], c0[9], a1[9], c1[9];
    #pragma unroll
    for (int l = 0; l < 9; ++l) a0[l] = x1p[l * MUL];
    #pragma unroll
    for (int m = 0; m < 9; ++m) c0[m] = x2p[m * MUL];
    #pragma unroll
    for (int l = 0; l < 9; ++l) a1[l] = x1p[(9 + l) * MUL];
    #pragma unroll
    for (int m = 0; m < 9; ++m) c1[m] = x2p[(9 + m) * MUL];
    x1p += 2 * 9 * MUL;   // now points at row b0+2
    x2p += 2 * 9 * MUL;

    // ---- W fragments once per block (cg 8KB, L2-hot after first blocks) ----
    // A[mt][ks]: row n = 16*mt + (lane&15), k = 32*ks + 8*(lane>>4) + j
    bf16x8 afrag[2][3];
    #pragma unroll
    for (int mt = 0; mt < 2; ++mt) {
        const int n = 16 * mt + (lane & 15);
        #pragma unroll
        for (int ks = 0; ks < 3; ++ks) {
            #pragma unroll
            for (int j = 0; j < 8; ++j) {
                const int k = 32 * ks + 8 * (lane >> 4) + j;
                float w = (k < 81 && n < D3) ? cg[k * D3 + n] : 0.0f;
                afrag[mt][ks][j] = (__bf16)w;
            }
        }
    }

    const int fg = chunk * FCHUNK + wv * 64 + (lane & 15);
    float* op = out + (size_t)b0 * (D3 * MUL) + fg;

    uint4* row = reinterpret_cast<uint4*>(smem + tid * ROWB);
    const char* bbase0 = smem + (size_t)(wv * 64 + (lane & 15)) * ROWB
                              + (lane >> 4) * 16;

    for (int r = 0; r < RPB; ++r) {
        // ---- S products (row r) -> bf16 -> own LDS row (96 k + pad) ----
        #pragma unroll
        for (int ch = 0; ch < 12; ++ch) {
            bf16x8 v;
            #pragma unroll
            for (int j = 0; j < 8; ++j) {
                const int k = ch * 8 + j;
                const float p = (k < 81) ? a0[k / 9] * c0[k % 9] : 0.0f;
                v[j] = (__bf16)p;
            }
            row[ch] = __builtin_bit_cast(uint4, v);
        }

        // ---- rotate buffers: row r+1 becomes current ----
        #pragma unroll
        for (int l = 0; l < 9; ++l) a0[l] = a1[l];
        #pragma unroll
        for (int m = 0; m < 9; ++m) c0[m] = c1[m];

        // ---- prefetch row r+2 (two iterations of slack) ----
        if (r + 2 < RPB) {
            #pragma unroll
            for (int l = 0; l < 9; ++l) a1[l] = x1p[l * MUL];
            #pragma unroll
            for (int m = 0; m < 9; ++m) c1[m] = x2p[m * MUL];
        }
        x1p += 9 * MUL;
        x2p += 9 * MUL;

        // ---- B fragments from own rows, MFMA ----
        f32x4 acc[2][4];
        #pragma unroll
        for (int mt = 0; mt < 2; ++mt)
            #pragma unroll
            for (int ft = 0; ft < 4; ++ft)
                acc[mt][ft] = (f32x4){0.f, 0.f, 0.f, 0.f};

        #pragma unroll
        for (int ft = 0; ft < 4; ++ft) {
            const char* bb = bbase0 + ft * 16 * ROWB;
            #pragma unroll
            for (int ks = 0; ks < 3; ++ks) {
                bf16x8 bfrag = *reinterpret_cast<const bf16x8*>(bb + ks * 64);
                acc[0][ft] = __builtin_amdgcn_mfma_f32_16x16x32_bf16(
                    afrag[0][ks], bfrag, acc[0][ft], 0, 0, 0);
                acc[1][ft] = __builtin_amdgcn_mfma_f32_16x16x32_bf16(
                    afrag[1][ks], bfrag, acc[1][ft], 0, 0, 0);
            }
        }

        // ---- stores (NT: write-around, zero-reuse stream) ----
        #pragma unroll
        for (int mt = 0; mt < 2; ++mt) {
            #pragma unroll
            for (int rr = 0; rr < 4; ++rr) {
                const int n = 16 * mt + (lane >> 4) * 4 + rr;
                if (n < D3) {
                    #pragma unroll
                    for (int ft = 0; ft < 4; ++ft)
                        __builtin_nontemporal_store(
                            acc[mt][ft][rr], op + (size_t)n * MUL + ft * 16);
                }
            }
        }
        op += D3 * MUL;
    }
}

extern "C" void kernel_launch(void* const* d_in, const int* in_sizes, int n_in,
                              void* d_out, int out_size, void* d_ws, size_t ws_size,
                              hipStream_t stream) {
    const float* x1 = (const float*)d_in[0];
    const float* x2 = (const float*)d_in[1];
    const float* cg = (const float*)d_in[2];
    float* out = (float*)d_out;

    dim3 grid((BATCH / RPB) * 2);
    dim3 block(256);
    tp_kernel<<<grid, block, FCHUNK * ROWB, stream>>>(x1, x2, cg, out);
}

// Round 10
// 831.373 us; speedup vs baseline: 1.0647x; 1.0647x over previous
//
#include <hip/hip_runtime.h>

// out[b,n,f] = sum_{l,m} x1[b,l,f] * x2[b,m,f] * cg[l,m,n]
// B=50000, d1=d2=9, d3=25, MUL=512, fp32 in/out.
//
// MFMA formulation: per b, out[n,f] = sum_k W[k,n]*S[k,f], k=(l,m) pad 96;
// S=x1*x2 bf16 in LDS (row per f-channel, pitch 208B); W=cg bf16 regs;
// mfma_f32_16x16x32_bf16 fp32-accum. No barriers: all LDS is intra-wave
// (per-wave DS ops execute in program order; compiler orders via lgkmcnt).
// Ledger: R7 858us (RPB=10, 1-deep prefetch, NT dword stores);
//         R8 874 (L2 stores); R9 885 (2-deep prefetch, RPB=20).
// R10: store-WIDTH experiment. Old epilogue = 25 scattered 4B/lane stores
// (4x64B segments per instr). New: dump acc into the wave's own dead S
// region as [n][f_local] fp32, read back contiguous float4/thread, emit 7
// NT dwordx4 stores (16B/lane, 256B contiguous per n-row). Matches the
// 16B/lane shape of the 6.3TB/s copy/fill references. Predict 650-730us
// if store shape was the limiter.

#define BATCH 50000
#define MUL   512
#define D3    25
#define FCHUNK 256
#define ROWB  208
#define RPB   10

typedef __bf16 bf16x8 __attribute__((ext_vector_type(8)));
typedef float  f32x4  __attribute__((ext_vector_type(4)));

__global__ void __launch_bounds__(256) tp_kernel(
    const float* __restrict__ x1,
    const float* __restrict__ x2,
    const float* __restrict__ cg,
    float* __restrict__ out) {

    extern __shared__ char smem[];

    const int bg    = blockIdx.x >> 1;   // row-group index
    const int chunk = blockIdx.x & 1;    // which 256 f-channels
    const int tid   = threadIdx.x;
    const int lane  = tid & 63;
    const int wv    = tid >> 6;
    const int b0    = bg * RPB;

    // ---- W fragments once per block (cg 8KB, L2-hot after first blocks) ----
    // A[mt][ks]: row n = 16*mt + (lane&15), k = 32*ks + 8*(lane>>4) + j
    bf16x8 afrag[2][3];
    #pragma unroll
    for (int mt = 0; mt < 2; ++mt) {
        const int n = 16 * mt + (lane & 15);
        #pragma unroll
        for (int ks = 0; ks < 3; ++ks) {
            #pragma unroll
            for (int j = 0; j < 8; ++j) {
                const int k = 32 * ks + 8 * (lane >> 4) + j;
                float w = (k < 81 && n < D3) ? cg[k * D3 + n] : 0.0f;
                afrag[mt][ks][j] = (__bf16)w;
            }
        }
    }

    const int fl = chunk * FCHUNK + tid;               // this thread's channel
    const float* x1p = x1 + (size_t)b0 * (9 * MUL) + fl;
    const float* x2p = x2 + (size_t)b0 * (9 * MUL) + fl;
    // per-wave output base: row n=0, f = chunk*256 + wv*64
    float* op = out + (size_t)b0 * (D3 * MUL) + chunk * FCHUNK + wv * 64;

    float a[9], c[9];
    #pragma unroll
    for (int l = 0; l < 9; ++l) a[l] = x1p[l * MUL];
    #pragma unroll
    for (int m = 0; m < 9; ++m) c[m] = x2p[m * MUL];

    uint4* row = reinterpret_cast<uint4*>(smem + tid * ROWB);
    const char* bbase0 = smem + (size_t)(wv * 64 + (lane & 15)) * ROWB
                              + (lane >> 4) * 16;
    // wave's private LDS region, reused for the transposed output tile
    float* twave = reinterpret_cast<float*>(smem + (size_t)wv * 64 * ROWB);

    for (int r = 0; r < RPB; ++r) {
        // ---- S products (row r) -> bf16 -> own LDS row (96 k + pad) ----
        #pragma unroll
        for (int ch = 0; ch < 12; ++ch) {
            bf16x8 v;
            #pragma unroll
            for (int j = 0; j < 8; ++j) {
                const int k = ch * 8 + j;
                const float p = (k < 81) ? a[k / 9] * c[k % 9] : 0.0f;
                v[j] = (__bf16)p;
            }
            row[ch] = __builtin_bit_cast(uint4, v);
        }

        // ---- prefetch next row's x (latency hides under MFMA below) ----
        x1p += 9 * MUL;
        x2p += 9 * MUL;
        if (r != RPB - 1) {
            #pragma unroll
            for (int l = 0; l < 9; ++l) a[l] = x1p[l * MUL];
            #pragma unroll
            for (int m = 0; m < 9; ++m) c[m] = x2p[m * MUL];
        }

        // ---- B fragments from own rows, MFMA ----
        f32x4 acc[2][4];
        #pragma unroll
        for (int mt = 0; mt < 2; ++mt)
            #pragma unroll
            for (int ft = 0; ft < 4; ++ft)
                acc[mt][ft] = (f32x4){0.f, 0.f, 0.f, 0.f};

        #pragma unroll
        for (int ft = 0; ft < 4; ++ft) {
            const char* bb = bbase0 + ft * 16 * ROWB;
            #pragma unroll
            for (int ks = 0; ks < 3; ++ks) {
                bf16x8 bfrag = *reinterpret_cast<const bf16x8*>(bb + ks * 64);
                acc[0][ft] = __builtin_amdgcn_mfma_f32_16x16x32_bf16(
                    afrag[0][ks], bfrag, acc[0][ft], 0, 0, 0);
                acc[1][ft] = __builtin_amdgcn_mfma_f32_16x16x32_bf16(
                    afrag[1][ks], bfrag, acc[1][ft], 0, 0, 0);
            }
        }

        // ---- epilogue A: acc -> wave's LDS tile [n][f_local] (S is dead) ----
        #pragma unroll
        for (int mt = 0; mt < 2; ++mt) {
            #pragma unroll
            for (int rr = 0; rr < 4; ++rr) {
                const int n = 16 * mt + (lane >> 4) * 4 + rr;
                if (n < D3) {
                    #pragma unroll
                    for (int ft = 0; ft < 4; ++ft)
                        twave[n * 64 + ft * 16 + (lane & 15)] = acc[mt][ft][rr];
                }
            }
        }

        // ---- epilogue B: contiguous float4 per thread -> NT dwordx4 ----
        #pragma unroll
        for (int idx = 0; idx < 7; ++idx) {
            const int p = idx * 64 + lane;        // 400 = 25 rows x 16 quads
            if (p < D3 * 16) {
                const int n = p >> 4;
                const int q = p & 15;
                const f32x4 v = *reinterpret_cast<const f32x4*>(
                    twave + n * 64 + q * 4);
                float* dst = op + (size_t)n * MUL + q * 4;
                __builtin_nontemporal_store(v.x, dst + 0);
                __builtin_nontemporal_store(v.y, dst + 1);
                __builtin_nontemporal_store(v.z, dst + 2);
                __builtin_nontemporal_store(v.w, dst + 3);
            }
        }
        op += D3 * MUL;
    }
}

extern "C" void kernel_launch(void* const* d_in, const int* in_sizes, int n_in,
                              void* d_out, int out_size, void* d_ws, size_t ws_size,
                              hipStream_t stream) {
    const float* x1 = (const float*)d_in[0];
    const float* x2 = (const float*)d_in[1];
    const float* cg = (const float*)d_in[2];
    float* out = (float*)d_out;

    dim3 grid((BATCH / RPB) * 2);
    dim3 block(256);
    tp_kernel<<<grid, block, FCHUNK * ROWB, stream>>>(x1, x2, cg, out);
}